// Round 16
// baseline (63.855 us; speedup 1.0000x reference)
//
#include <hip/hip_runtime.h>
#include <math.h>

#define K 2048           // time buckets
#define NFOC 512         // focal blocks in kA (256 thr)
#define NPW  2048        // pw blocks in kA
#define NA (NFOC + NPW)
#define NHB 256          // hist blocks in kB (1024 thr)

// ---------------- kA: pure streaming — focal blocks + pw blocks --------------
__global__ __launch_bounds__(256) void kA(
    const float* __restrict__ rp, const int* __restrict__ rl,
    const float* __restrict__ pw,
    double* __restrict__ partF, double* __restrict__ partP) {
    int bid = blockIdx.x, tid = threadIdx.x;
    __shared__ double lds[256];
    double acc = 0.0;

    if (bid < NFOC) {
        // ---- pure focal: 2048 f4-pairs per block, 8 per thread ----
        const float4* rp4 = (const float4*)rp + (long long)bid * 2048;
        const int4*   rl4 = (const int4*)rl + (long long)bid * 2048;
        float fs = 0.f;
#define FOC(pc, lc)                                                           \
        {                                                                     \
            float pp = pc; float tt = (float)(lc);                            \
            float ce = fmaxf(pp, 0.f) - pp * tt                               \
                     + __logf(1.f + __expf(-fabsf(pp)));                      \
            float ptv = __expf(-ce); float om = 1.f - ptv;                    \
            fs += (0.25f * tt + 0.75f * (1.f - tt)) * om * om * ce;           \
        }
        {
            float4 P0 = rp4[tid], P1 = rp4[tid + 256], P2 = rp4[tid + 512], P3 = rp4[tid + 768];
            int4   L0 = rl4[tid], L1 = rl4[tid + 256], L2 = rl4[tid + 512], L3 = rl4[tid + 768];
            FOC(P0.x, L0.x) FOC(P0.y, L0.y) FOC(P0.z, L0.z) FOC(P0.w, L0.w)
            FOC(P1.x, L1.x) FOC(P1.y, L1.y) FOC(P1.z, L1.z) FOC(P1.w, L1.w)
            FOC(P2.x, L2.x) FOC(P2.y, L2.y) FOC(P2.z, L2.z) FOC(P2.w, L2.w)
            FOC(P3.x, L3.x) FOC(P3.y, L3.y) FOC(P3.z, L3.z) FOC(P3.w, L3.w)
        }
        {
            float4 P0 = rp4[tid + 1024], P1 = rp4[tid + 1280], P2 = rp4[tid + 1536], P3 = rp4[tid + 1792];
            int4   L0 = rl4[tid + 1024], L1 = rl4[tid + 1280], L2 = rl4[tid + 1536], L3 = rl4[tid + 1792];
            FOC(P0.x, L0.x) FOC(P0.y, L0.y) FOC(P0.z, L0.z) FOC(P0.w, L0.w)
            FOC(P1.x, L1.x) FOC(P1.y, L1.y) FOC(P1.z, L1.z) FOC(P1.w, L1.w)
            FOC(P2.x, L2.x) FOC(P2.y, L2.y) FOC(P2.z, L2.z) FOC(P2.w, L2.w)
            FOC(P3.x, L3.x) FOC(P3.y, L3.y) FOC(P3.z, L3.z) FOC(P3.w, L3.w)
        }
#undef FOC
        acc = (double)fs;
    } else {
        // ---- pure pw sum-of-squares: 2048 f4 per block, 8 per thread ----
        const float4* base = (const float4*)pw + (long long)(bid - NFOC) * 2048;
        float s0 = 0.f, s1 = 0.f;
#define SQ4(V, S) { S += (V).x * (V).x + (V).y * (V).y                        \
                       + (V).z * (V).z + (V).w * (V).w; }
        {
            float4 a0 = base[tid], a1 = base[tid + 256], a2 = base[tid + 512], a3 = base[tid + 768];
            SQ4(a0, s0) SQ4(a1, s1) SQ4(a2, s0) SQ4(a3, s1)
        }
        {
            float4 a0 = base[tid + 1024], a1 = base[tid + 1280], a2 = base[tid + 1536], a3 = base[tid + 1792];
            SQ4(a0, s0) SQ4(a1, s1) SQ4(a2, s0) SQ4(a3, s1)
        }
#undef SQ4
        acc = (double)s0 + (double)s1;
    }

    lds[tid] = acc; __syncthreads();
    for (int s = 128; s > 0; s >>= 1) {
        if (tid < s) lds[tid] += lds[tid + s];
        __syncthreads();
    }
    if (tid == 0) {
        if (bid < NFOC) partF[bid] = lds[0];
        else            partP[bid - NFOC] = lds[0];
    }
}

// ---------------- kB: pure histogram role ------------------------------------
__global__ __launch_bounds__(1024) void kB(
    const float* __restrict__ tm, const float* __restrict__ h,
    const int* __restrict__ ev,
    float* __restrict__ btot, unsigned* __restrict__ bev,
    double* __restrict__ partH) {
    __shared__ __align__(16) char smem[16384];
    float*    hist   = (float*)smem;              // [K]
    unsigned* histev = (unsigned*)(smem + 8192);  // [K]
    double*   lds    = (double*)smem;             // reused after flush
    int bid = blockIdx.x, tid = threadIdx.x;
    double seh = 0.0;
    int ne = 0;

    for (int j = tid; j < K; j += 1024) { hist[j] = 0.f; histev[j] = 0u; }
    __syncthreads();
    const float4* tm4 = (const float4*)tm + (long long)bid * 4096;
    const float4* h4  = (const float4*)h  + (long long)bid * 4096;
    const int4*   ev4 = (const int4*)ev  + (long long)bid * 4096;
#define HL(tc, hc, ec)                                                        \
    {                                                                         \
        unsigned b = (unsigned)((tc) * (float)K);                             \
        if (b > K - 1u) b = K - 1u;                                           \
        atomicAdd(&hist[b], __expf(hc));                                      \
        if (ec) { atomicAdd(&histev[b], 1u);                                  \
                  seh += (double)(hc); ne += 1; }                             \
    }
    for (int i = tid; i < 4096; i += 2048) {      // 2 iters; 6 loads in flight
        float4 T0 = tm4[i],        H0 = h4[i];
        int4   E0 = ev4[i];
        float4 T1 = tm4[i + 1024], H1 = h4[i + 1024];
        int4   E1 = ev4[i + 1024];
        HL(T0.x, H0.x, E0.x) HL(T0.y, H0.y, E0.y)
        HL(T0.z, H0.z, E0.z) HL(T0.w, H0.w, E0.w)
        HL(T1.x, H1.x, E1.x) HL(T1.y, H1.y, E1.y)
        HL(T1.z, H1.z, E1.z) HL(T1.w, H1.w, E1.w)
    }
#undef HL
    __syncthreads();
    for (int j = tid; j < K; j += 1024) {         // guarded flush
        float v = hist[j];
        if (v != 0.f) atomicAdd(&btot[j], v);
        unsigned c = histev[j];
        if (c) atomicAdd(&bev[j], c);
    }
    __syncthreads();
    lds[tid] = seh; lds[1024 + tid] = (double)ne; __syncthreads();
    for (int s = 512; s > 0; s >>= 1) {
        if (tid < s) { lds[tid] += lds[tid + s]; lds[1024 + tid] += lds[1024 + tid + s]; }
        __syncthreads();
    }
    if (tid == 0) { partH[bid * 2 + 0] = lds[0]; partH[bid * 2 + 1] = lds[1024]; }
}

// ---------------- kTail: pb + scan + dot + reduce + combine ------------------
__global__ __launch_bounds__(1024) void kTail(
    const float* __restrict__ btot, const unsigned* __restrict__ bev,
    const double* __restrict__ partF, const double* __restrict__ partP,
    const double* __restrict__ partH, const float* __restrict__ pb, int nb,
    const float* __restrict__ lsv, const float* __restrict__ lrv,
    const float* __restrict__ lgv, int n, float* __restrict__ out) {
    __shared__ double lds[2048];
    int tid = threadIdx.x;
    float v0 = btot[2 * tid], v1 = btot[2 * tid + 1];
    unsigned c0 = bev[2 * tid], c1 = bev[2 * tid + 1];
    lds[tid] = (double)v0 + (double)v1; __syncthreads();
    for (int off = 1; off < 1024; off <<= 1) {
        double a = (tid >= off) ? lds[tid - off] : 0.0;
        __syncthreads();
        lds[tid] += a;
        __syncthreads();
    }
    double run = (tid == 0) ? 0.0 : lds[tid - 1];
    double r0 = run + (double)v0;
    double r1 = r0 + (double)v1;
    double dot = 0.0;
    if (c0) dot += (double)c0 * log(r0);
    if (c1) dot += (double)c1 * log(r1);
    __syncthreads();

    double foc = 0.0, seh = 0.0, nev = 0.0;
    double reg = partP[tid] + partP[tid + 1024];   // 2048 pw partials
    if (tid < NFOC) foc = partF[tid];
    if (tid < NHB) { seh = partH[tid * 2 + 0]; nev = partH[tid * 2 + 1]; }
    {
        int nb4 = nb >> 2;                         // pb: 1024 float4s
        if (tid < nb4) {
            float4 v = ((const float4*)pb)[tid];
            float s = v.x * v.x + v.y * v.y + v.z * v.z + v.w * v.w;
            reg += (double)s;
        }
    }

    lds[tid] = dot; lds[1024 + tid] = foc; __syncthreads();
    for (int s = 512; s > 0; s >>= 1) {
        if (tid < s) { lds[tid] += lds[tid + s]; lds[1024 + tid] += lds[1024 + tid + s]; }
        __syncthreads();
    }
    double dotT = lds[0], focT = lds[1024]; __syncthreads();
    lds[tid] = reg; lds[1024 + tid] = seh; __syncthreads();
    for (int s = 512; s > 0; s >>= 1) {
        if (tid < s) { lds[tid] += lds[tid + s]; lds[1024 + tid] += lds[1024 + tid + s]; }
        __syncthreads();
    }
    double regT = lds[0], sehT = lds[1024]; __syncthreads();
    lds[tid] = nev; __syncthreads();
    for (int s = 512; s > 0; s >>= 1) {
        if (tid < s) lds[tid] += lds[tid + s];
        __syncthreads();
    }
    if (tid == 0) {
        double neT = lds[0];
        double cox = sehT - dotT;                  // Σ_events (h - logS)
        double surv = -cox / (neT + 1e-8);
        double rec = focT / (double)n;
        double rg = 1e-4 * regT;
        double a = (double)lsv[0], b = (double)lrv[0], c = (double)lgv[0];
        double sp = exp(-a), rpv = exp(-b), gp = exp(-c);
        double total = sp * surv + rpv * rec + gp * rg + a + b + c;
        out[0] = (float)total;
        out[1] = (float)surv;
        out[2] = (float)rec;
        out[3] = (float)rg;
        out[4] = (float)sp;
        out[5] = (float)rpv;
    }
}

extern "C" void kernel_launch(void* const* d_in, const int* in_sizes, int n_in,
                              void* d_out, int out_size, void* d_ws, size_t ws_size,
                              hipStream_t stream) {
    const float* h   = (const float*)d_in[0];
    const float* rp  = (const float*)d_in[1];
    const float* tm  = (const float*)d_in[2];
    const int*   ev  = (const int*)d_in[3];
    const int*   rl  = (const int*)d_in[4];
    const float* pw  = (const float*)d_in[5];
    const float* pb  = (const float*)d_in[6];
    const float* lsv = (const float*)d_in[7];
    const float* lrv = (const float*)d_in[8];
    const float* lgv = (const float*)d_in[9];
    int n  = in_sizes[0];
    int nb = in_sizes[6];
    float* out = (float*)d_out;

    float*    btot  = (float*)d_ws;                // K floats
    unsigned* bev   = (unsigned*)(btot + K);       // K uints
    double*   partF = (double*)(bev + K);          // NFOC doubles
    double*   partP = partF + NFOC;                // NPW doubles
    double*   partH = partP + NPW;                 // NHB*2 doubles

    hipMemsetAsync(btot, 0, (size_t)K * 8, stream);   // btot + bev
    kA<<<NA, 256, 0, stream>>>(rp, rl, pw, partF, partP);
    kB<<<NHB, 1024, 0, stream>>>(tm, h, ev, btot, bev, partH);
    kTail<<<1, 1024, 0, stream>>>(btot, bev, partF, partP, partH, pb, nb,
                                  lsv, lrv, lgv, n, out);
}

// Round 17
// 63.732 us; speedup vs baseline: 1.0019x; 1.0019x over previous
//
#include <hip/hip_runtime.h>
#include <math.h>

#define K 2048           // time buckets
#define NHB 512          // histogram-role blocks, 512 thr
#define NWB 512          // focal-role blocks, 512 thr
#define NB (NHB + NWB)
#define PWH 3072         // pw float4s per hist block
#define PWF 5120         // pw float4s per focal block; 512*(3072+5120)=nw/4

typedef float f32x4 __attribute__((ext_vector_type(4)));
typedef int   i32x4 __attribute__((ext_vector_type(4)));

// 6-load cluster: forced MLP=6, compiler cannot serialize inside one asm block
#define LOAD6(d0,d1,d2,d3,d4,d5, a0,a1,a2,a3,a4,a5)                           \
    asm volatile(                                                             \
        "global_load_dwordx4 %0, %6, off\n\t"                                 \
        "global_load_dwordx4 %1, %7, off\n\t"                                 \
        "global_load_dwordx4 %2, %8, off\n\t"                                 \
        "global_load_dwordx4 %3, %9, off\n\t"                                 \
        "global_load_dwordx4 %4, %10, off\n\t"                                \
        "global_load_dwordx4 %5, %11, off\n\t"                                \
        "s_waitcnt vmcnt(0)"                                                  \
        : "=&v"(d0), "=&v"(d1), "=&v"(d2), "=&v"(d3), "=&v"(d4), "=&v"(d5)    \
        : "v"(a0), "v"(a1), "v"(a2), "v"(a3), "v"(a4), "v"(a5))

#define LOAD5(d0,d1,d2,d3,d4, a0,a1,a2,a3,a4)                                 \
    asm volatile(                                                             \
        "global_load_dwordx4 %0, %5, off\n\t"                                 \
        "global_load_dwordx4 %1, %6, off\n\t"                                 \
        "global_load_dwordx4 %2, %7, off\n\t"                                 \
        "global_load_dwordx4 %3, %8, off\n\t"                                 \
        "global_load_dwordx4 %4, %9, off\n\t"                                 \
        "s_waitcnt vmcnt(0)"                                                  \
        : "=&v"(d0), "=&v"(d1), "=&v"(d2), "=&v"(d3), "=&v"(d4)               \
        : "v"(a0), "v"(a1), "v"(a2), "v"(a3), "v"(a4))

#define LOAD4(d0,d1,d2,d3, a0,a1,a2,a3)                                       \
    asm volatile(                                                             \
        "global_load_dwordx4 %0, %4, off\n\t"                                 \
        "global_load_dwordx4 %1, %5, off\n\t"                                 \
        "global_load_dwordx4 %2, %6, off\n\t"                                 \
        "global_load_dwordx4 %3, %7, off\n\t"                                 \
        "s_waitcnt vmcnt(0)"                                                  \
        : "=&v"(d0), "=&v"(d1), "=&v"(d2), "=&v"(d3)                          \
        : "v"(a0), "v"(a1), "v"(a2), "v"(a3))

// ---------------- k1: fused, staggered, asm-clustered loads ------------------
__global__ __launch_bounds__(512) void k1(
    const float* __restrict__ tm, const float* __restrict__ h,
    const int* __restrict__ ev, int n,
    const float* __restrict__ rp, const int* __restrict__ rl,
    const float* __restrict__ pw,
    float* __restrict__ btot, unsigned* __restrict__ bev,
    double* __restrict__ partW, double* __restrict__ partH) {
    __shared__ __align__(16) char smem[16384];
    float*    hist   = (float*)smem;              // [K]
    unsigned* histev = (unsigned*)(smem + 8192);  // [K]
    double*   lds    = (double*)smem;             // reused after flush
    int bid = blockIdx.x, tid = threadIdx.x;
    double foc = 0.0, reg = 0.0, seh = 0.0;
    int ne = 0;

#define SQ4(V) {                                                              \
        float s_ = (V)[0] * (V)[0] + (V)[1] * (V)[1]                          \
                 + (V)[2] * (V)[2] + (V)[3] * (V)[3];                         \
        reg += (double)s_; }

    if (bid < NHB) {
        // ---- phase 1: histogram (tm,h,ev), 2 iters x 6-load cluster ----
        for (int j = tid; j < K; j += 512) { hist[j] = 0.f; histev[j] = 0u; }
        __syncthreads();
        const f32x4* tm4 = (const f32x4*)tm + (long long)bid * 2048;
        const f32x4* h4  = (const f32x4*)h  + (long long)bid * 2048;
        const i32x4* ev4 = (const i32x4*)ev + (long long)bid * 2048;
#define HL(tc, hc, ec)                                                        \
        {                                                                     \
            unsigned b = (unsigned)((tc) * (float)K);                         \
            if (b > K - 1u) b = K - 1u;                                       \
            atomicAdd(&hist[b], __expf(hc));                                  \
            if (ec) { atomicAdd(&histev[b], 1u);                              \
                      seh += (double)(hc); ne += 1; }                         \
        }
#pragma unroll
        for (int it = 0; it < 2; ++it) {
            int i0 = it * 1024 + tid, i1 = i0 + 512;
            f32x4 T0, T1, H0, H1; i32x4 E0, E1;
            LOAD6(T0, T1, H0, H1, E0, E1,
                  tm4 + i0, tm4 + i1, h4 + i0, h4 + i1, ev4 + i0, ev4 + i1);
            HL(T0[0], H0[0], E0[0]) HL(T0[1], H0[1], E0[1])
            HL(T0[2], H0[2], E0[2]) HL(T0[3], H0[3], E0[3])
            HL(T1[0], H1[0], E1[0]) HL(T1[1], H1[1], E1[1])
            HL(T1[2], H1[2], E1[2]) HL(T1[3], H1[3], E1[3])
        }
#undef HL
        __syncthreads();
        for (int j = tid; j < K; j += 512) {       // guarded flush
            float v = hist[j];
            if (v != 0.f) atomicAdd(&btot[j], v);
            unsigned c = histev[j];
            if (c) atomicAdd(&bev[j], c);
        }
        // ---- phase 2: pw slice, one 6-load cluster ----
        const f32x4* mypw = (const f32x4*)pw + (long long)bid * PWH;
        {
            f32x4 V0, V1, V2, V3, V4, V5;
            LOAD6(V0, V1, V2, V3, V4, V5,
                  mypw + tid,        mypw + tid + 512,  mypw + tid + 1024,
                  mypw + tid + 1536, mypw + tid + 2048, mypw + tid + 2560);
            SQ4(V0) SQ4(V1) SQ4(V2) SQ4(V3) SQ4(V4) SQ4(V5)
        }
    } else {
        int widx = bid - NHB;
        // ---- phase 1: pw slice, 2 x 5-load clusters ----
        const f32x4* mypw = (const f32x4*)pw
                          + (long long)NHB * PWH + (long long)widx * PWF;
        {
            f32x4 V0, V1, V2, V3, V4;
            LOAD5(V0, V1, V2, V3, V4,
                  mypw + tid,        mypw + tid + 512,  mypw + tid + 1024,
                  mypw + tid + 1536, mypw + tid + 2048);
            SQ4(V0) SQ4(V1) SQ4(V2) SQ4(V3) SQ4(V4)
            f32x4 W0, W1, W2, W3, W4;
            LOAD5(W0, W1, W2, W3, W4,
                  mypw + tid + 2560, mypw + tid + 3072, mypw + tid + 3584,
                  mypw + tid + 4096, mypw + tid + 4608);
            SQ4(W0) SQ4(W1) SQ4(W2) SQ4(W3) SQ4(W4)
        }
        // ---- phase 2: focal (rp,rl), 2 iters x 4-load cluster ----
        const f32x4* rp4 = (const f32x4*)rp + (long long)widx * 2048;
        const i32x4* rl4 = (const i32x4*)rl + (long long)widx * 2048;
#define FOC(pc, lc)                                                           \
        {                                                                     \
            float pp = pc; float tt = (float)(lc);                            \
            float ce = fmaxf(pp, 0.f) - pp * tt                               \
                     + __logf(1.f + __expf(-fabsf(pp)));                      \
            float ptv = __expf(-ce); float om = 1.f - ptv;                    \
            foc += (double)((0.25f * tt + 0.75f * (1.f - tt)) * om * om * ce);\
        }
#pragma unroll
        for (int it = 0; it < 2; ++it) {
            int i0 = it * 1024 + tid, i1 = i0 + 512;
            f32x4 P0, P1; i32x4 L0, L1;
            LOAD4(P0, P1, L0, L1, rp4 + i0, rp4 + i1, rl4 + i0, rl4 + i1);
            FOC(P0[0], L0[0]) FOC(P0[1], L0[1]) FOC(P0[2], L0[2]) FOC(P0[3], L0[3])
            FOC(P1[0], L1[0]) FOC(P1[1], L1[1]) FOC(P1[2], L1[2]) FOC(P1[3], L1[3])
        }
#undef FOC
    }
#undef SQ4

    __syncthreads();                               // LDS hist no longer needed
    lds[tid] = foc; lds[512 + tid] = reg; __syncthreads();
    for (int s = 256; s > 0; s >>= 1) {
        if (tid < s) { lds[tid] += lds[tid + s]; lds[512 + tid] += lds[512 + tid + s]; }
        __syncthreads();
    }
    if (tid == 0) { partW[bid * 2 + 0] = lds[0]; partW[bid * 2 + 1] = lds[512]; }
    if (bid < NHB) {
        __syncthreads();
        lds[tid] = seh; lds[512 + tid] = (double)ne; __syncthreads();
        for (int s = 256; s > 0; s >>= 1) {
            if (tid < s) { lds[tid] += lds[tid + s]; lds[512 + tid] += lds[512 + tid + s]; }
            __syncthreads();
        }
        if (tid == 0) { partH[bid * 2 + 0] = lds[0]; partH[bid * 2 + 1] = lds[512]; }
    }
}

// ---------------- kTail: pb + scan + dot + reduce + combine ------------------
__global__ __launch_bounds__(1024) void kTail(
    const float* __restrict__ btot, const unsigned* __restrict__ bev,
    const double* __restrict__ partW, const double* __restrict__ partH,
    const float* __restrict__ pb, int nb,
    const float* __restrict__ lsv, const float* __restrict__ lrv,
    const float* __restrict__ lgv, int n, float* __restrict__ out) {
    __shared__ double lds[2048];
    int tid = threadIdx.x;
    float v0 = btot[2 * tid], v1 = btot[2 * tid + 1];
    unsigned c0 = bev[2 * tid], c1 = bev[2 * tid + 1];
    lds[tid] = (double)v0 + (double)v1; __syncthreads();
    for (int off = 1; off < 1024; off <<= 1) {
        double a = (tid >= off) ? lds[tid - off] : 0.0;
        __syncthreads();
        lds[tid] += a;
        __syncthreads();
    }
    double run = (tid == 0) ? 0.0 : lds[tid - 1];
    double r0 = run + (double)v0;
    double r1 = r0 + (double)v1;
    double dot = 0.0;
    if (c0) dot += (double)c0 * log(r0);
    if (c1) dot += (double)c1 * log(r1);
    __syncthreads();

    double foc = partW[tid * 2 + 0];               // NB = 1024 partials
    double reg = partW[tid * 2 + 1];
    double seh = 0.0, nev = 0.0;
    if (tid < NHB) { seh = partH[tid * 2 + 0]; nev = partH[tid * 2 + 1]; }
    {
        int nb4 = nb >> 2;                         // pb: 1024 float4s
        if (tid < nb4) {
            float4 v = ((const float4*)pb)[tid];
            float s = v.x * v.x + v.y * v.y + v.z * v.z + v.w * v.w;
            reg += (double)s;
        }
    }

    lds[tid] = dot; lds[1024 + tid] = foc; __syncthreads();
    for (int s = 512; s > 0; s >>= 1) {
        if (tid < s) { lds[tid] += lds[tid + s]; lds[1024 + tid] += lds[1024 + tid + s]; }
        __syncthreads();
    }
    double dotT = lds[0], focT = lds[1024]; __syncthreads();
    lds[tid] = reg; lds[1024 + tid] = seh; __syncthreads();
    for (int s = 512; s > 0; s >>= 1) {
        if (tid < s) { lds[tid] += lds[tid + s]; lds[1024 + tid] += lds[1024 + tid + s]; }
        __syncthreads();
    }
    double regT = lds[0], sehT = lds[1024]; __syncthreads();
    lds[tid] = nev; __syncthreads();
    for (int s = 512; s > 0; s >>= 1) {
        if (tid < s) lds[tid] += lds[tid + s];
        __syncthreads();
    }
    if (tid == 0) {
        double neT = lds[0];
        double cox = sehT - dotT;                  // Σ_events (h - logS)
        double surv = -cox / (neT + 1e-8);
        double rec = focT / (double)n;
        double rg = 1e-4 * regT;
        double a = (double)lsv[0], b = (double)lrv[0], c = (double)lgv[0];
        double sp = exp(-a), rpv = exp(-b), gp = exp(-c);
        double total = sp * surv + rpv * rec + gp * rg + a + b + c;
        out[0] = (float)total;
        out[1] = (float)surv;
        out[2] = (float)rec;
        out[3] = (float)rg;
        out[4] = (float)sp;
        out[5] = (float)rpv;
    }
}

extern "C" void kernel_launch(void* const* d_in, const int* in_sizes, int n_in,
                              void* d_out, int out_size, void* d_ws, size_t ws_size,
                              hipStream_t stream) {
    const float* h   = (const float*)d_in[0];
    const float* rp  = (const float*)d_in[1];
    const float* tm  = (const float*)d_in[2];
    const int*   ev  = (const int*)d_in[3];
    const int*   rl  = (const int*)d_in[4];
    const float* pw  = (const float*)d_in[5];
    const float* pb  = (const float*)d_in[6];
    const float* lsv = (const float*)d_in[7];
    const float* lrv = (const float*)d_in[8];
    const float* lgv = (const float*)d_in[9];
    int n  = in_sizes[0];
    int nb = in_sizes[6];
    float* out = (float*)d_out;

    float*    btot  = (float*)d_ws;                // K floats
    unsigned* bev   = (unsigned*)(btot + K);       // K uints
    double*   partW = (double*)(bev + K);          // NB*2 doubles
    double*   partH = partW + 2 * NB;              // NHB*2 doubles

    hipMemsetAsync(btot, 0, (size_t)K * 8, stream);   // btot + bev
    k1<<<NB, 512, 0, stream>>>(tm, h, ev, n, rp, rl, pw,
                               btot, bev, partW, partH);
    kTail<<<1, 1024, 0, stream>>>(btot, bev, partW, partH, pb, nb,
                                  lsv, lrv, lgv, n, out);
}

// Round 18
// 53.467 us; speedup vs baseline: 1.1943x; 1.1920x over previous
//
#include <hip/hip_runtime.h>
#include <math.h>

#define K 2048           // time buckets
#define NHB 256          // histogram-role blocks, 1024 thr
#define NWB 256          // focal-role blocks, 1024 thr
#define NB (NHB + NWB)
#define PS_H 6144        // pw float4s per hist block
#define PS_W 10240       // pw float4s per work block (256*(6144+10240) = nw/4)

// adjacent-pair read: thread reads float4[2p] and float4[2p+1] (32 B contiguous)
#define PAIR(arr, p, A, B) float4 A = (arr)[2*(p)]; float4 B = (arr)[2*(p)+1];

// ---------------- k1: R10 structure + pair-contiguous reads ------------------
__global__ __launch_bounds__(1024) void k1(
    const float* __restrict__ tm, const float* __restrict__ h,
    const int* __restrict__ ev, int n,
    const float* __restrict__ rp, const int* __restrict__ rl,
    const float* __restrict__ pw, int nw,
    const float* __restrict__ pb, int nb,
    float* __restrict__ btot, unsigned* __restrict__ bev,
    double* __restrict__ partW, double* __restrict__ partH) {
    __shared__ __align__(16) char smem[16384];
    float*    hist   = (float*)smem;              // [K]
    unsigned* histev = (unsigned*)(smem + 8192);  // [K]
    double*   lds    = (double*)smem;             // reused after flush
    int bid = blockIdx.x, tid = threadIdx.x;
    double foc = 0.0, reg = 0.0, seh = 0.0;
    int ne = 0;

    const float4* mypw;
    int npair;                                     // pw pairs per thread

#define SQ4(V) {                                                              \
        float s_ = (V).x * (V).x + (V).y * (V).y                              \
                 + (V).z * (V).z + (V).w * (V).w;                             \
        reg += (double)s_; }

    if (bid < NHB) {
        // ---- histogram role: tm/h/ev = 2048 pairs per block, 2 per thread --
        for (int j = tid; j < K; j += 1024) { hist[j] = 0.f; histev[j] = 0u; }
        __syncthreads();
        const float4* tm4 = (const float4*)tm + (long long)bid * 4096;
        const float4* h4  = (const float4*)h  + (long long)bid * 4096;
        const int4*   ev4 = (const int4*)ev  + (long long)bid * 4096;
#define HL(tc, hc, ec)                                                        \
        {                                                                     \
            unsigned b = (unsigned)((tc) * (float)K);                         \
            if (b > K - 1u) b = K - 1u;                                       \
            atomicAdd(&hist[b], __expf(hc));                                  \
            if (ec) { atomicAdd(&histev[b], 1u);                              \
                      seh += (double)(hc); ne += 1; }                         \
        }
#pragma unroll
        for (int g = 0; g < 2; ++g) {
            int p = tid + g * 1024;                // pair index
            PAIR(tm4, p, Ta, Tb)
            PAIR(h4,  p, Ha, Hb)
            int4 Ea = ev4[2*p], Eb = ev4[2*p+1];
            HL(Ta.x, Ha.x, Ea.x) HL(Ta.y, Ha.y, Ea.y)
            HL(Ta.z, Ha.z, Ea.z) HL(Ta.w, Ha.w, Ea.w)
            HL(Tb.x, Hb.x, Eb.x) HL(Tb.y, Hb.y, Eb.y)
            HL(Tb.z, Hb.z, Eb.z) HL(Tb.w, Hb.w, Eb.w)
        }
#undef HL
        __syncthreads();
        for (int j = tid; j < K; j += 1024) {      // guarded flush
            float v = hist[j];
            if (v != 0.f) atomicAdd(&btot[j], v);
            unsigned c = histev[j];
            if (c) atomicAdd(&bev[j], c);
        }
        mypw  = (const float4*)pw + (long long)bid * PS_H;
        npair = 3;                                 // 3072 pairs / 1024 thr
    } else {
        // ---- focal role: rp/rl = 2048 pairs per block, 2 per thread --------
        int widx = bid - NHB;
        const float4* rp4 = (const float4*)rp + (long long)widx * 4096;
        const int4*   rl4 = (const int4*)rl + (long long)widx * 4096;
#define FOC(pc, lc)                                                           \
        {                                                                     \
            float pp = pc; float tt = (float)(lc);                            \
            float ce = fmaxf(pp, 0.f) - pp * tt                               \
                     + __logf(1.f + __expf(-fabsf(pp)));                      \
            float ptv = __expf(-ce); float om = 1.f - ptv;                    \
            foc += (double)((0.25f * tt + 0.75f * (1.f - tt)) * om * om * ce);\
        }
#pragma unroll
        for (int g = 0; g < 2; ++g) {
            int p = tid + g * 1024;
            PAIR(rp4, p, Pa, Pb)
            int4 La = rl4[2*p], Lb = rl4[2*p+1];
            FOC(Pa.x, La.x) FOC(Pa.y, La.y) FOC(Pa.z, La.z) FOC(Pa.w, La.w)
            FOC(Pb.x, Lb.x) FOC(Pb.y, Lb.y) FOC(Pb.z, Lb.z) FOC(Pb.w, Lb.w)
        }
#undef FOC
        mypw  = (const float4*)pw + (long long)NHB * PS_H + (long long)widx * PS_W;
        npair = 5;                                 // 5120 pairs / 1024 thr
    }

    // ---- common: pw slice, adjacent-pair reads ----
    for (int g = 0; g < npair; ++g) {
        int p = tid + g * 1024;
        PAIR(mypw, p, Va, Vb)
        SQ4(Va) SQ4(Vb)
    }
    if (bid == NHB) {                              // pb: 512 pairs
        int npb = nb >> 3;                         // pairs
        if (tid < npb) {
            PAIR(((const float4*)pb), tid, Ba, Bb)
            SQ4(Ba) SQ4(Bb)
        }
    }
#undef SQ4
#undef PAIR

    __syncthreads();                               // LDS hist no longer needed
    lds[tid] = foc; lds[1024 + tid] = reg; __syncthreads();
    for (int s = 512; s > 0; s >>= 1) {
        if (tid < s) { lds[tid] += lds[tid + s]; lds[1024 + tid] += lds[1024 + tid + s]; }
        __syncthreads();
    }
    if (tid == 0) { partW[bid * 2 + 0] = lds[0]; partW[bid * 2 + 1] = lds[1024]; }
    if (bid < NHB) {
        __syncthreads();
        lds[tid] = seh; lds[1024 + tid] = (double)ne; __syncthreads();
        for (int s = 512; s > 0; s >>= 1) {
            if (tid < s) { lds[tid] += lds[tid + s]; lds[1024 + tid] += lds[1024 + tid + s]; }
            __syncthreads();
        }
        if (tid == 0) { partH[bid * 2 + 0] = lds[0]; partH[bid * 2 + 1] = lds[1024]; }
    }
}

// ---------------- kTail: scan + dot + reduce + combine -----------------------
__global__ __launch_bounds__(1024) void kTail(
    const float* __restrict__ btot, const unsigned* __restrict__ bev,
    const double* __restrict__ partW, const double* __restrict__ partH,
    const float* __restrict__ lsv, const float* __restrict__ lrv,
    const float* __restrict__ lgv, int n, float* __restrict__ out) {
    __shared__ double lds[2048];
    int tid = threadIdx.x;
    float v0 = btot[2 * tid], v1 = btot[2 * tid + 1];
    unsigned c0 = bev[2 * tid], c1 = bev[2 * tid + 1];
    lds[tid] = (double)v0 + (double)v1; __syncthreads();
    for (int off = 1; off < 1024; off <<= 1) {
        double a = (tid >= off) ? lds[tid - off] : 0.0;
        __syncthreads();
        lds[tid] += a;
        __syncthreads();
    }
    double run = (tid == 0) ? 0.0 : lds[tid - 1];
    double r0 = run + (double)v0;
    double r1 = r0 + (double)v1;
    double dot = 0.0;
    if (c0) dot += (double)c0 * log(r0);
    if (c1) dot += (double)c1 * log(r1);
    __syncthreads();

    double foc = 0.0, reg = 0.0, seh = 0.0, nev = 0.0;
    if (tid < NB)  { foc = partW[tid * 2 + 0]; reg = partW[tid * 2 + 1]; }
    if (tid < NHB) { seh = partH[tid * 2 + 0]; nev = partH[tid * 2 + 1]; }

    lds[tid] = dot; lds[1024 + tid] = foc; __syncthreads();
    for (int s = 512; s > 0; s >>= 1) {
        if (tid < s) { lds[tid] += lds[tid + s]; lds[1024 + tid] += lds[1024 + tid + s]; }
        __syncthreads();
    }
    double dotT = lds[0], focT = lds[1024]; __syncthreads();
    lds[tid] = reg; lds[1024 + tid] = seh; __syncthreads();
    for (int s = 512; s > 0; s >>= 1) {
        if (tid < s) { lds[tid] += lds[tid + s]; lds[1024 + tid] += lds[1024 + tid + s]; }
        __syncthreads();
    }
    double regT = lds[0], sehT = lds[1024]; __syncthreads();
    lds[tid] = nev; __syncthreads();
    for (int s = 512; s > 0; s >>= 1) {
        if (tid < s) lds[tid] += lds[tid + s];
        __syncthreads();
    }
    if (tid == 0) {
        double neT = lds[0];
        double cox = sehT - dotT;                  // Σ_events (h - logS)
        double surv = -cox / (neT + 1e-8);
        double rec = focT / (double)n;
        double rg = 1e-4 * regT;
        double a = (double)lsv[0], b = (double)lrv[0], c = (double)lgv[0];
        double sp = exp(-a), rpv = exp(-b), gp = exp(-c);
        double total = sp * surv + rpv * rec + gp * rg + a + b + c;
        out[0] = (float)total;
        out[1] = (float)surv;
        out[2] = (float)rec;
        out[3] = (float)rg;
        out[4] = (float)sp;
        out[5] = (float)rpv;
    }
}

extern "C" void kernel_launch(void* const* d_in, const int* in_sizes, int n_in,
                              void* d_out, int out_size, void* d_ws, size_t ws_size,
                              hipStream_t stream) {
    const float* h   = (const float*)d_in[0];
    const float* rp  = (const float*)d_in[1];
    const float* tm  = (const float*)d_in[2];
    const int*   ev  = (const int*)d_in[3];
    const int*   rl  = (const int*)d_in[4];
    const float* pw  = (const float*)d_in[5];
    const float* pb  = (const float*)d_in[6];
    const float* lsv = (const float*)d_in[7];
    const float* lrv = (const float*)d_in[8];
    const float* lgv = (const float*)d_in[9];
    int n  = in_sizes[0];
    int nw = in_sizes[5];
    int nb = in_sizes[6];
    float* out = (float*)d_out;

    float*    btot  = (float*)d_ws;                // K floats
    unsigned* bev   = (unsigned*)(btot + K);       // K uints
    double*   partW = (double*)(bev + K);          // NB*2 doubles
    double*   partH = partW + 2 * NB;              // NHB*2 doubles

    hipMemsetAsync(btot, 0, (size_t)K * 8, stream);   // btot + bev
    k1<<<NB, 1024, 0, stream>>>(tm, h, ev, n, rp, rl, pw, nw, pb, nb,
                                btot, bev, partW, partH);
    kTail<<<1, 1024, 0, stream>>>(btot, bev, partW, partH, lsv, lrv, lgv, n, out);
}